// Round 3
// baseline (101.347 us; speedup 1.0000x reference)
//
#include <hip/hip_runtime.h>

// Problem constants (fixed by setup_inputs)
#define NB 16
#define NC 64
#define TX 128
#define TY 128
#define DD 768
#define BK 32
#define NT (DD / BK) // 24 K-steps

typedef __bf16 bf16_t;
typedef __bf16 bf16x8 __attribute__((ext_vector_type(8)));
typedef __bf16 bf16x4 __attribute__((ext_vector_type(4)));
typedef float  f32x4  __attribute__((ext_vector_type(4)));

// LDS tile: 128 rows x 32 bf16 = 64 B/row. XOR-swizzle the 16B slot index
// with (row>>1)&3: fragment reads (16 lanes stride-64B) land at the free
// 2-way conflict level instead of 8-way.
__device__ __forceinline__ unsigned swz(unsigned r, unsigned kb) {
  return r * 64u + ((((kb >> 4) & 3u) ^ ((r >> 1) & 3u)) << 4) + (kb & 15u);
}

// fp32x4 -> bf16x4 via compiler cast (packs to v_cvt_pk_bf16_f32), 8B store
__device__ __forceinline__ void cvt_store(void* dst, float4 v) {
  bf16x4 q;
  q[0] = (bf16_t)v.x; q[1] = (bf16_t)v.y; q[2] = (bf16_t)v.z; q[3] = (bf16_t)v.w;
  *(bf16x4*)dst = q;
}

// xs fp32 -> bf16 one-shot conversion into workspace
__global__ __launch_bounds__(256) void cvt_xs_kernel(const float* __restrict__ xs,
                                                     bf16_t* __restrict__ ws) {
  int i = blockIdx.x * 256 + threadIdx.x;   // one float4 per thread
  float4 v = ((const float4*)xs)[i];
  cvt_store(ws + (size_t)i * 4, v);
}

template<bool PRE>
__device__ __forceinline__ bf16x8 load_afrag(const bf16_t* pb16, const float* pf32, int koff) {
  if constexpr (PRE) {
    return *(const bf16x8*)(pb16 + koff);
  } else {
    float4 v0 = *(const float4*)(pf32 + koff);
    float4 v1 = *(const float4*)(pf32 + koff + 4);
    bf16x8 q;
    q[0] = (bf16_t)v0.x; q[1] = (bf16_t)v0.y; q[2] = (bf16_t)v0.z; q[3] = (bf16_t)v0.w;
    q[4] = (bf16_t)v1.x; q[5] = (bf16_t)v1.y; q[6] = (bf16_t)v1.z; q[7] = (bf16_t)v1.w;
    return q;
  }
}

template<bool PRE>
__global__ __launch_bounds__(256, 3) void ur_score_kernel(
    const float* __restrict__ xs, const bf16_t* __restrict__ xsb,
    const float* __restrict__ ys, float* __restrict__ out)
{
  // B-only double-buffered LDS: [buf][128 rows * 64 B]
  __shared__ char lds[2][8192];
  __shared__ float wsum[4];

  // XCD-aware remap: u%16 == b -> all 64 blocks sharing a batch land on one
  // XCD; xs[b] (bf16: 196 KB) stays L2-resident there.
  const int u  = blockIdx.x;
  const int b  = u & 15;
  const int c  = u >> 4;
  const int bc = b * NC + c;

  const int tid  = threadIdx.x;
  const int lane = tid & 63;
  const int w    = tid >> 6;         // wave 0..3

  const float4* Bg = (const float4*)(ys + (size_t)bc * TY * DD);

  // A-fragment direct addresses: lane l holds A[row=l&15][k=(l>>4)*8 ..+8]
  const unsigned arow = (unsigned)(w * 32 + (lane & 15));
  const unsigned ak   = ((unsigned)(lane >> 4)) << 3;       // elem offset
  const bf16_t* A0b = nullptr; const bf16_t* A1b = nullptr;
  const float*  A0f = nullptr; const float*  A1f = nullptr;
  if constexpr (PRE) {
    A0b = xsb + (size_t)(b * TX + arow) * DD + ak;
    A1b = A0b + (size_t)16 * DD;
  } else {
    A0f = xs + (size_t)(b * TX + arow) * DD + ak;
    A1f = A0f + (size_t)16 * DD;
  }

  f32x4 acc[2][8];
  #pragma unroll
  for (int m = 0; m < 2; ++m)
    #pragma unroll
    for (int n = 0; n < 8; ++n)
      #pragma unroll
      for (int k = 0; k < 4; ++k)
        acc[m][n][k] = 0.0f;

  // B staging coords: 1024 float4 per tile / 256 threads = 4 each
  unsigned rr[4], jj[4], soff[4];
  #pragma unroll
  for (int i = 0; i < 4; ++i) {
    unsigned idx = (unsigned)tid + i * 256u;
    rr[i] = idx >> 3;
    jj[i] = idx & 7u;
    soff[i] = swz(rr[i], jj[i] * 8u);
  }

  const unsigned kb = ((unsigned)lane >> 4) << 4;   // B frag byte offset in row
  const unsigned rB = (unsigned)(lane & 15);        // B frag base row (y)

  float4 pbv0[4], pbv1[4];
  bf16x8 af00, af01, af10, af11;   // [set][m]

  // ---- prologue ----
  #pragma unroll
  for (int i = 0; i < 4; ++i) pbv0[i] = Bg[rr[i] * (DD / 4) + jj[i]];
  af00 = load_afrag<PRE>(A0b, A0f, 0);
  af01 = load_afrag<PRE>(A1b, A1f, 0);
  #pragma unroll
  for (int i = 0; i < 4; ++i) pbv1[i] = Bg[rr[i] * (DD / 4) + (BK / 4) + jj[i]];
  #pragma unroll
  for (int i = 0; i < 4; ++i) cvt_store(&lds[0][soff[i]], pbv0[i]);
  asm volatile("s_waitcnt lgkmcnt(0)" ::: "memory");
  __builtin_amdgcn_s_barrier();
  asm volatile("" ::: "memory");

  // Per K-step (store-late / T14):
  //  (b) ds_read B frags   (c) MFMA (af waited with counted vmcnt; B prefetch
  //  stays in flight)      (d) cvt_store tile t+1 (loads got a full iter in
  //  flight)               (e) issue af(t+1) then pb(t+2)  (f) lgkm-only barrier
  #define KSTEP(T, LC, LN, AFC0, AFC1, AFN0, AFN1, PBC, PBN)                       \
  {                                                                                 \
    bf16x8 bfr[8];                                                                  \
    _Pragma("unroll")                                                               \
    for (int n = 0; n < 8; ++n)                                                     \
      bfr[n] = *(const bf16x8*)&LC[swz(rB + n * 16u, kb)];                          \
    _Pragma("unroll")                                                               \
    for (int n = 0; n < 8; ++n)                                                     \
      acc[0][n] = __builtin_amdgcn_mfma_f32_16x16x32_bf16(AFC0, bfr[n], acc[0][n], 0, 0, 0); \
    _Pragma("unroll")                                                               \
    for (int n = 0; n < 8; ++n)                                                     \
      acc[1][n] = __builtin_amdgcn_mfma_f32_16x16x32_bf16(AFC1, bfr[n], acc[1][n], 0, 0, 0); \
    if ((T) + 1 < NT) {                                                             \
      _Pragma("unroll")                                                             \
      for (int i = 0; i < 4; ++i) cvt_store(&LN[soff[i]], PBN[i]);                  \
      AFN0 = load_afrag<PRE>(A0b, A0f, ((T) + 1) * BK);                             \
      AFN1 = load_afrag<PRE>(A1b, A1f, ((T) + 1) * BK);                             \
    }                                                                               \
    if ((T) + 2 < NT) {                                                             \
      _Pragma("unroll")                                                             \
      for (int i = 0; i < 4; ++i)                                                   \
        PBC[i] = Bg[rr[i] * (DD / 4) + ((T) + 2) * (BK / 4) + jj[i]];               \
    }                                                                               \
    asm volatile("s_waitcnt lgkmcnt(0)" ::: "memory");                              \
    __builtin_amdgcn_s_barrier();                                                   \
    asm volatile("" ::: "memory");                                                  \
  }

  for (int tt = 0; tt < NT; tt += 2) {
    KSTEP(tt,     lds[0], lds[1], af00, af01, af10, af11, pbv0, pbv1);
    KSTEP(tt + 1, lds[1], lds[0], af10, af11, af00, af01, pbv1, pbv0);
  }
  #undef KSTEP

  // ---- reduction: max over y, sum over x ----
  // acc element (m,n,i) at lane l: x = w*32 + m*16 + (l>>4)*4 + i, y = n*16 + (l&15)
  float rm[2][4];
  #pragma unroll
  for (int m = 0; m < 2; ++m)
    #pragma unroll
    for (int i = 0; i < 4; ++i) {
      float v = acc[m][0][i];
      #pragma unroll
      for (int n = 1; n < 8; ++n) v = fmaxf(v, acc[m][n][i]);
      rm[m][i] = v;
    }
  #pragma unroll
  for (int mask = 1; mask < 16; mask <<= 1)
    #pragma unroll
    for (int m = 0; m < 2; ++m)
      #pragma unroll
      for (int i = 0; i < 4; ++i)
        rm[m][i] = fmaxf(rm[m][i], __shfl_xor(rm[m][i], mask, 64));

  float ps = 0.0f;
  #pragma unroll
  for (int m = 0; m < 2; ++m)
    #pragma unroll
    for (int i = 0; i < 4; ++i) ps += rm[m][i];
  ps += __shfl_xor(ps, 16, 64);
  ps += __shfl_xor(ps, 32, 64);

  if (lane == 0) wsum[w] = ps;
  __syncthreads();
  if (tid == 0) out[bc] = wsum[0] + wsum[1] + wsum[2] + wsum[3];
}

extern "C" void kernel_launch(void* const* d_in, const int* in_sizes, int n_in,
                              void* d_out, int out_size, void* d_ws, size_t ws_size,
                              hipStream_t stream) {
  const float* xs = (const float*)d_in[0];
  const float* ys = (const float*)d_in[1];
  float* out = (float*)d_out;
  const size_t need = (size_t)NB * TX * DD * sizeof(bf16_t);  // 3.1 MB
  if (ws_size >= need) {
    bf16_t* xsb = (bf16_t*)d_ws;
    cvt_xs_kernel<<<dim3(NB * TX * DD / 4 / 256), dim3(256), 0, stream>>>(xs, xsb);
    ur_score_kernel<true><<<dim3(NB * NC), dim3(256), 0, stream>>>(xs, xsb, ys, out);
  } else {
    ur_score_kernel<false><<<dim3(NB * NC), dim3(256), 0, stream>>>(xs, nullptr, ys, out);
  }
}

// Round 4
// 90.452 us; speedup vs baseline: 1.1205x; 1.1205x over previous
//
#include <hip/hip_runtime.h>

// Problem constants (fixed by setup_inputs)
#define NB 16
#define NC 64
#define TX 128
#define TY 128
#define DD 768
#define BK 32
#define NT (DD / BK) // 24 K-steps

typedef __bf16 bf16_t;
typedef __bf16 bf16x8 __attribute__((ext_vector_type(8)));
typedef __bf16 bf16x4 __attribute__((ext_vector_type(4)));
typedef float  f32x4  __attribute__((ext_vector_type(4)));

// LDS tile: 128 rows x 32 bf16 = 64 B/row. XOR-swizzle the 16B slot index
// with (row>>1)&3: fragment reads (16 lanes stride-64B) land at the free
// 2-way conflict level instead of 8-way.
__device__ __forceinline__ unsigned swz(unsigned r, unsigned kb) {
  return r * 64u + ((((kb >> 4) & 3u) ^ ((r >> 1) & 3u)) << 4) + (kb & 15u);
}

// fp32x4 -> bf16x4 (packs to v_cvt_pk_bf16_f32), 8B store
__device__ __forceinline__ void cvt_store(void* dst, f32x4 v) {
  bf16x4 q;
  q[0] = (bf16_t)v[0]; q[1] = (bf16_t)v[1]; q[2] = (bf16_t)v[2]; q[3] = (bf16_t)v[3];
  *(bf16x4*)dst = q;
}

__global__ __launch_bounds__(256, 4) void ur_score_kernel(
    const float* __restrict__ xs, const float* __restrict__ ys,
    float* __restrict__ out)
{
  // [buf][A=0/B=1][128 rows * 64 B] -- 32.8 KB/block, 4 blocks/CU = 131 KB
  __shared__ char lds[2][2][8192];
  __shared__ float wsum[4];

  // XCD-aware remap: u%16 == b -> u%8 == b%8, all same-b blocks on one XCD;
  // xs[b] (393 KB fp32) stays L2-resident there.
  const int u  = blockIdx.x;
  const int b  = u & 15;
  const int c  = u >> 4;
  const int bc = b * NC + c;

  const int tid  = threadIdx.x;
  const int lane = tid & 63;
  const int w    = tid >> 6;         // wave 0..3

  // Staging geometry: thread stages float4 chunks i=0..3 at
  //   row = r0 + 32*i, float-offset = row*DD + t*BK + j0*4.
  // The swizzle XOR term is i-invariant (16*i % 4 == 0), so the LDS offset
  // is soff0 + 2048*i -- compile-time immediates, minimal address regs.
  const unsigned r0 = (unsigned)tid >> 3;   // 0..31
  const unsigned j0 = (unsigned)tid & 7u;   // 0..7
  const unsigned soff0 = swz(r0, j0 * 8u);
  const float* Ap = xs + (size_t)b  * TX * DD + r0 * DD + j0 * 4;
  const float* Bp = ys + (size_t)bc * TY * DD + r0 * DD + j0 * 4;

  f32x4 acc[2][8];
  #pragma unroll
  for (int m = 0; m < 2; ++m)
    #pragma unroll
    for (int n = 0; n < 8; ++n)
      #pragma unroll
      for (int k = 0; k < 4; ++k)
        acc[m][n][k] = 0.0f;

  f32x4 pa[4], pb[4];

  // ---- prologue: tile0 -> regs -> lds[0]; tile1 -> regs ----
  #pragma unroll
  for (int i = 0; i < 4; ++i) {
    pa[i] = __builtin_nontemporal_load((const f32x4*)(Ap + i * 32 * DD));
    pb[i] = __builtin_nontemporal_load((const f32x4*)(Bp + i * 32 * DD));
  }
  #pragma unroll
  for (int i = 0; i < 4; ++i) {
    cvt_store(&lds[0][0][soff0 + 2048u * i], pa[i]);
    cvt_store(&lds[0][1][soff0 + 2048u * i], pb[i]);
  }
  #pragma unroll
  for (int i = 0; i < 4; ++i) {
    pa[i] = __builtin_nontemporal_load((const f32x4*)(Ap + BK + i * 32 * DD));
    pb[i] = __builtin_nontemporal_load((const f32x4*)(Bp + BK + i * 32 * DD));
  }
  // barrier WITHOUT vmem drain: only LDS ops must be visible
  asm volatile("s_waitcnt lgkmcnt(0)" ::: "memory");
  __builtin_amdgcn_s_barrier();
  asm volatile("" ::: "memory");

  const unsigned kb = ((unsigned)lane >> 4) << 4;          // 0/16/32/48 B
  const unsigned rA = (unsigned)(w * 32 + (lane & 15));    // A rows this wave
  const unsigned rB = (unsigned)(lane & 15);               // B rows (y)
  const unsigned aoff = swz(rA, kb);   // A frag base; +16 rows = +1024 B
  const unsigned boff = swz(rB, kb);   // B frag base; +16n rows = +1024n B

  int cur = 0;
  for (int t = 0; t < NT; ++t) {
    // 1) convert + write tile t+1 (its loads got a full iteration in flight)
    if (t + 1 < NT) {
      #pragma unroll
      for (int i = 0; i < 4; ++i) {
        cvt_store(&lds[cur ^ 1][0][soff0 + 2048u * i], pa[i]);
        cvt_store(&lds[cur ^ 1][1][soff0 + 2048u * i], pb[i]);
      }
    }
    // 2) issue tile t+2 loads; they stay in flight across the raw barrier
    if (t + 2 < NT) {
      #pragma unroll
      for (int i = 0; i < 4; ++i) {
        pa[i] = __builtin_nontemporal_load((const f32x4*)(Ap + (t + 2) * BK + i * 32 * DD));
        pb[i] = __builtin_nontemporal_load((const f32x4*)(Bp + (t + 2) * BK + i * 32 * DD));
      }
    }
    // 3) fragments + MFMA on buf[cur]
    bf16x8 af0 = *(const bf16x8*)&lds[cur][0][aoff];
    bf16x8 af1 = *(const bf16x8*)&lds[cur][0][aoff + 1024u];
    bf16x8 bfr[8];
    #pragma unroll
    for (int n = 0; n < 8; ++n)
      bfr[n] = *(const bf16x8*)&lds[cur][1][boff + 1024u * n];
    #pragma unroll
    for (int n = 0; n < 8; ++n)
      acc[0][n] = __builtin_amdgcn_mfma_f32_16x16x32_bf16(af0, bfr[n], acc[0][n], 0, 0, 0);
    #pragma unroll
    for (int n = 0; n < 8; ++n)
      acc[1][n] = __builtin_amdgcn_mfma_f32_16x16x32_bf16(af1, bfr[n], acc[1][n], 0, 0, 0);

    // barrier with LDS-only drain (B prefetch stays in flight)
    asm volatile("s_waitcnt lgkmcnt(0)" ::: "memory");
    __builtin_amdgcn_s_barrier();
    asm volatile("" ::: "memory");
    cur ^= 1;
  }

  // ---- reduction: max over y, sum over x ----
  // acc element (m,n,i) at lane l: x = w*32 + m*16 + (l>>4)*4 + i, y = n*16 + (l&15)
  float rm[2][4];
  #pragma unroll
  for (int m = 0; m < 2; ++m)
    #pragma unroll
    for (int i = 0; i < 4; ++i) {
      float v = acc[m][0][i];
      #pragma unroll
      for (int n = 1; n < 8; ++n) v = fmaxf(v, acc[m][n][i]);
      rm[m][i] = v;
    }
  #pragma unroll
  for (int mask = 1; mask < 16; mask <<= 1)
    #pragma unroll
    for (int m = 0; m < 2; ++m)
      #pragma unroll
      for (int i = 0; i < 4; ++i)
        rm[m][i] = fmaxf(rm[m][i], __shfl_xor(rm[m][i], mask, 64));

  float ps = 0.0f;
  #pragma unroll
  for (int m = 0; m < 2; ++m)
    #pragma unroll
    for (int i = 0; i < 4; ++i) ps += rm[m][i];
  ps += __shfl_xor(ps, 16, 64);
  ps += __shfl_xor(ps, 32, 64);

  if (lane == 0) wsum[w] = ps;
  __syncthreads();
  if (tid == 0) out[bc] = wsum[0] + wsum[1] + wsum[2] + wsum[3];
}

extern "C" void kernel_launch(void* const* d_in, const int* in_sizes, int n_in,
                              void* d_out, int out_size, void* d_ws, size_t ws_size,
                              hipStream_t stream) {
  const float* xs = (const float*)d_in[0];
  const float* ys = (const float*)d_in[1];
  float* out = (float*)d_out;
  ur_score_kernel<<<dim3(NB * NC), dim3(256), 0, stream>>>(xs, ys, out);
}

// Round 5
// 81.994 us; speedup vs baseline: 1.2360x; 1.1032x over previous
//
#include <hip/hip_runtime.h>

// Problem constants (fixed by setup_inputs)
#define NB 16
#define NC 64
#define TX 128
#define TY 128
#define DD 768
#define BK 32
#define NT (DD / BK) // 24 K-steps

typedef __bf16 bf16_t;
typedef __bf16 bf16x8 __attribute__((ext_vector_type(8)));
typedef __bf16 bf16x4 __attribute__((ext_vector_type(4)));
typedef float  f32x4  __attribute__((ext_vector_type(4)));

// LDS tile: 128 rows x 32 bf16 = 64 B/row. XOR-swizzle the 16B slot index
// with (row>>1)&3: fragment reads (16 lanes stride-64B) land at the free
// 2-way conflict level instead of 8-way.
__device__ __forceinline__ unsigned swz(unsigned r, unsigned kb) {
  return r * 64u + ((((kb >> 4) & 3u) ^ ((r >> 1) & 3u)) << 4) + (kb & 15u);
}

// fp32x4 -> bf16x4 (packs to v_cvt_pk_bf16_f32), 8B store
__device__ __forceinline__ void cvt_store(void* dst, f32x4 v) {
  bf16x4 q;
  q[0] = (bf16_t)v[0]; q[1] = (bf16_t)v[1]; q[2] = (bf16_t)v[2]; q[3] = (bf16_t)v[3];
  *(bf16x4*)dst = q;
}

// 8 waves x 64 = 512 threads; each wave owns a 16x128 output strip.
// 2 blocks/CU => 16 waves/CU, per-thread live set ~76 VGPR (< 128, no spill).
__global__ __launch_bounds__(512, 2) void ur_score_kernel(
    const float* __restrict__ xs, const float* __restrict__ ys,
    float* __restrict__ out)
{
  // [buf][A=0/B=1][128 rows * 64 B] -- 32.8 KB/block
  __shared__ char lds[2][2][8192];
  __shared__ float wsum[8];

  // XCD-aware remap: u%16 == b -> u%8 == b%8, all same-b blocks on one XCD;
  // xs[b] (393 KB fp32) stays L2-resident there.
  const int u  = blockIdx.x;
  const int b  = u & 15;
  const int c  = u >> 4;
  const int bc = b * NC + c;

  const int tid  = threadIdx.x;
  const int lane = tid & 63;
  const int w    = tid >> 6;         // wave 0..7

  // Staging: 1024 float4/tile per operand, 512 threads -> 2 chunks each at
  //   row = r0 + 64*i  (i=0,1), float-offset = row*DD + t*BK + j0*4.
  // Swizzle XOR term is i-invariant (row+64 -> (row>>1)&3 unchanged), so the
  // LDS offset is soff0 + 4096*i.
  const unsigned r0 = (unsigned)tid >> 3;   // 0..63
  const unsigned j0 = (unsigned)tid & 7u;   // 0..7
  const unsigned soff0 = swz(r0, j0 * 8u);
  const float* Ap = xs + (size_t)b  * TX * DD + r0 * DD + j0 * 4;
  const float* Bp = ys + (size_t)bc * TY * DD + r0 * DD + j0 * 4;

  f32x4 acc[8];
  #pragma unroll
  for (int n = 0; n < 8; ++n)
    #pragma unroll
    for (int k = 0; k < 4; ++k)
      acc[n][k] = 0.0f;

  f32x4 pa[2], pb[2];

  // ---- prologue: tile0 -> regs -> lds[0]; tile1 -> regs ----
  #pragma unroll
  for (int i = 0; i < 2; ++i) {
    pa[i] = *(const f32x4*)(Ap + i * 64 * DD);   // xs: cached (L2-resident)
    pb[i] = __builtin_nontemporal_load((const f32x4*)(Bp + i * 64 * DD));
  }
  #pragma unroll
  for (int i = 0; i < 2; ++i) {
    cvt_store(&lds[0][0][soff0 + 4096u * i], pa[i]);
    cvt_store(&lds[0][1][soff0 + 4096u * i], pb[i]);
  }
  #pragma unroll
  for (int i = 0; i < 2; ++i) {
    pa[i] = *(const f32x4*)(Ap + BK + i * 64 * DD);
    pb[i] = __builtin_nontemporal_load((const f32x4*)(Bp + BK + i * 64 * DD));
  }
  // barrier WITHOUT vmem drain: only LDS ops must be visible
  asm volatile("s_waitcnt lgkmcnt(0)" ::: "memory");
  __builtin_amdgcn_s_barrier();
  asm volatile("" ::: "memory");

  const unsigned kb = ((unsigned)lane >> 4) << 4;          // 0/16/32/48 B
  const unsigned rA = (unsigned)(w * 16 + (lane & 15));    // A row this wave
  const unsigned rB = (unsigned)(lane & 15);               // B rows (y)
  const unsigned aoff = swz(rA, kb);
  const unsigned boff = swz(rB, kb);   // +16 rows = +1024 B

  int cur = 0;
  for (int t = 0; t < NT; ++t) {
    // 1) convert + write tile t+1 (its loads got a full iteration in flight)
    if (t + 1 < NT) {
      #pragma unroll
      for (int i = 0; i < 2; ++i) {
        cvt_store(&lds[cur ^ 1][0][soff0 + 4096u * i], pa[i]);
        cvt_store(&lds[cur ^ 1][1][soff0 + 4096u * i], pb[i]);
      }
    }
    // 2) issue tile t+2 loads; they stay in flight across the raw barrier
    if (t + 2 < NT) {
      #pragma unroll
      for (int i = 0; i < 2; ++i) {
        pa[i] = *(const f32x4*)(Ap + (t + 2) * BK + i * 64 * DD);
        pb[i] = __builtin_nontemporal_load((const f32x4*)(Bp + (t + 2) * BK + i * 64 * DD));
      }
    }
    // 3) fragments + MFMA on buf[cur]
    bf16x8 af = *(const bf16x8*)&lds[cur][0][aoff];
    bf16x8 bfr[8];
    #pragma unroll
    for (int n = 0; n < 8; ++n)
      bfr[n] = *(const bf16x8*)&lds[cur][1][boff + 1024u * n];
    #pragma unroll
    for (int n = 0; n < 8; ++n)
      acc[n] = __builtin_amdgcn_mfma_f32_16x16x32_bf16(af, bfr[n], acc[n], 0, 0, 0);

    // barrier with LDS-only drain (B prefetch stays in flight)
    asm volatile("s_waitcnt lgkmcnt(0)" ::: "memory");
    __builtin_amdgcn_s_barrier();
    asm volatile("" ::: "memory");
    cur ^= 1;
  }

  // ---- reduction: max over y, sum over x ----
  // acc element (n,i) at lane l: x = w*16 + (l>>4)*4 + i, y = n*16 + (l&15)
  float rm[4];
  #pragma unroll
  for (int i = 0; i < 4; ++i) {
    float v = acc[0][i];
    #pragma unroll
    for (int n = 1; n < 8; ++n) v = fmaxf(v, acc[n][i]);
    rm[i] = v;
  }
  // max across the 16 lanes holding different y for the same x-set
  #pragma unroll
  for (int mask = 1; mask < 16; mask <<= 1)
    #pragma unroll
    for (int i = 0; i < 4; ++i)
      rm[i] = fmaxf(rm[i], __shfl_xor(rm[i], mask, 64));

  // per-lane sum over its 4 distinct x rows, then combine the 4 lane-groups
  float ps = rm[0] + rm[1] + rm[2] + rm[3];
  ps += __shfl_xor(ps, 16, 64);
  ps += __shfl_xor(ps, 32, 64);

  if (lane == 0) wsum[w] = ps;
  __syncthreads();
  if (tid == 0) {
    float s = 0.0f;
    #pragma unroll
    for (int i = 0; i < 8; ++i) s += wsum[i];
    out[bc] = s;
  }
}

extern "C" void kernel_launch(void* const* d_in, const int* in_sizes, int n_in,
                              void* d_out, int out_size, void* d_ws, size_t ws_size,
                              hipStream_t stream) {
  const float* xs = (const float*)d_in[0];
  const float* ys = (const float*)d_in[1];
  float* out = (float*)d_out;
  ur_score_kernel<<<dim3(NB * NC), dim3(512), 0, stream>>>(xs, ys, out);
}

// Round 6
// 75.910 us; speedup vs baseline: 1.3351x; 1.0801x over previous
//
#include <hip/hip_runtime.h>

// Problem constants (fixed by setup_inputs)
#define NB 16
#define NC 64
#define TX 128
#define TY 128
#define DD 768
#define BK 64
#define NT (DD / BK) // 12 K-steps

typedef __bf16 bf16_t;
typedef __bf16 bf16x8 __attribute__((ext_vector_type(8)));
typedef __bf16 bf16x4 __attribute__((ext_vector_type(4)));
typedef float  f32x4  __attribute__((ext_vector_type(4)));

// LDS tile: 128 rows x 64 bf16 = 128 B/row. Guideline-4 XOR swizzle for
// 128B rows: 16B slot index ^= (row&7). Bank = f(slot) only (row*128 == 0
// mod 128B), so spreading slots spreads banks; frag b128 reads land at ~2x
// the per-bank minimum (~2-way, free per m136), writes stay 4-way.
__device__ __forceinline__ unsigned swz(unsigned r, unsigned byte) {
  return r * 128u + ((((byte >> 4) & 7u) ^ (r & 7u)) << 4) + (byte & 15u);
}

// fp32x4 -> bf16x4 (packs to v_cvt_pk_bf16_f32), 8B store
__device__ __forceinline__ void cvt_store(void* dst, f32x4 v) {
  bf16x4 q;
  q[0] = (bf16_t)v[0]; q[1] = (bf16_t)v[1]; q[2] = (bf16_t)v[2]; q[3] = (bf16_t)v[3];
  *(bf16x4*)dst = q;
}

// 8 waves x 64 = 512 threads; each wave owns a 16x128 output strip.
// 2 blocks/CU (128 KB LDS), 16 waves/CU; ~116 live VGPR < 128 cap.
__global__ __launch_bounds__(512, 2) void ur_score_kernel(
    const float* __restrict__ xs, const float* __restrict__ ys,
    float* __restrict__ out)
{
  // [buf][A=0/B=1][128 rows * 128 B] -- 64 KB/block
  __shared__ char lds[2][2][16384];
  __shared__ float wsum[8];

  // XCD-aware remap: u%16 == b -> u%8 == b%8, all same-b blocks on one XCD;
  // xs[b] (393 KB fp32) stays L2-resident there.
  const int u  = blockIdx.x;
  const int b  = u & 15;
  const int c  = u >> 4;
  const int bc = b * NC + c;

  const int tid  = threadIdx.x;
  const int lane = tid & 63;
  const int w    = tid >> 6;         // wave 0..7

  // Staging: 2048 float4/tile per operand, 512 threads -> 4 chunks each at
  //   row = r0 + 32*i (i=0..3), float-offset = row*DD + t*BK + j0*4.
  // (row&7) is i-invariant (32*i % 8 == 0) -> LDS offset = soff0 + 4096*i.
  const unsigned r0 = (unsigned)tid >> 4;   // 0..31
  const unsigned j0 = (unsigned)tid & 15u;  // 0..15
  const unsigned soff0 = swz(r0, j0 * 8u);
  const float* Ap = xs + (size_t)b  * TX * DD + r0 * DD + j0 * 4;
  const float* Bp = ys + (size_t)bc * TY * DD + r0 * DD + j0 * 4;

  f32x4 acc[8];
  #pragma unroll
  for (int n = 0; n < 8; ++n)
    #pragma unroll
    for (int k = 0; k < 4; ++k)
      acc[n][k] = 0.0f;

  f32x4 pa[4], pb[4];

  // ---- prologue: tile0 -> regs -> lds[0]; tile1 -> regs ----
  #pragma unroll
  for (int i = 0; i < 4; ++i) {
    pa[i] = *(const f32x4*)(Ap + i * 32 * DD);   // xs: cached (L2-resident)
    pb[i] = __builtin_nontemporal_load((const f32x4*)(Bp + i * 32 * DD));
  }
  #pragma unroll
  for (int i = 0; i < 4; ++i) {
    cvt_store(&lds[0][0][soff0 + 4096u * i], pa[i]);
    cvt_store(&lds[0][1][soff0 + 4096u * i], pb[i]);
  }
  #pragma unroll
  for (int i = 0; i < 4; ++i) {
    pa[i] = *(const f32x4*)(Ap + BK + i * 32 * DD);
    pb[i] = __builtin_nontemporal_load((const f32x4*)(Bp + BK + i * 32 * DD));
  }
  // barrier WITHOUT vmem drain: only LDS ops must be visible
  asm volatile("s_waitcnt lgkmcnt(0)" ::: "memory");
  __builtin_amdgcn_s_barrier();
  asm volatile("" ::: "memory");

  const unsigned kb = ((unsigned)lane >> 4) << 4;          // 0/16/32/48 B
  const unsigned rA = (unsigned)(w * 16 + (lane & 15));    // A row this wave
  const unsigned rB = (unsigned)(lane & 15);               // B rows (y)
  // Two K=32 sub-steps per tile; swizzle is not shift-invariant in the
  // byte offset, so compute both sub-step bases. Row+16n adds 2048n
  // (16 % 8 == 0 -> swizzle-invariant).
  const unsigned aoff0 = swz(rA, kb),      aoff1 = swz(rA, 64u + kb);
  const unsigned boff0 = swz(rB, kb),      boff1 = swz(rB, 64u + kb);

  int cur = 0;
  for (int t = 0; t < NT; ++t) {
    // 1) convert + write tile t+1 (its loads got a full iteration in flight)
    if (t + 1 < NT) {
      #pragma unroll
      for (int i = 0; i < 4; ++i) {
        cvt_store(&lds[cur ^ 1][0][soff0 + 4096u * i], pa[i]);
        cvt_store(&lds[cur ^ 1][1][soff0 + 4096u * i], pb[i]);
      }
    }
    // 2) issue tile t+2 loads; they stay in flight across the raw barrier
    if (t + 2 < NT) {
      #pragma unroll
      for (int i = 0; i < 4; ++i) {
        pa[i] = *(const f32x4*)(Ap + (t + 2) * BK + i * 32 * DD);
        pb[i] = __builtin_nontemporal_load((const f32x4*)(Bp + (t + 2) * BK + i * 32 * DD));
      }
    }
    // 3) fragments + MFMA on buf[cur] -- two K=32 sub-steps, 16 MFMA/phase
    {
      bf16x8 af0 = *(const bf16x8*)&lds[cur][0][aoff0];
      bf16x8 bfr[8];
      #pragma unroll
      for (int n = 0; n < 8; ++n)
        bfr[n] = *(const bf16x8*)&lds[cur][1][boff0 + 2048u * n];
      #pragma unroll
      for (int n = 0; n < 8; ++n)
        acc[n] = __builtin_amdgcn_mfma_f32_16x16x32_bf16(af0, bfr[n], acc[n], 0, 0, 0);
    }
    {
      bf16x8 af1 = *(const bf16x8*)&lds[cur][0][aoff1];
      bf16x8 bfr[8];
      #pragma unroll
      for (int n = 0; n < 8; ++n)
        bfr[n] = *(const bf16x8*)&lds[cur][1][boff1 + 2048u * n];
      #pragma unroll
      for (int n = 0; n < 8; ++n)
        acc[n] = __builtin_amdgcn_mfma_f32_16x16x32_bf16(af1, bfr[n], acc[n], 0, 0, 0);
    }

    // barrier with LDS-only drain (B prefetch stays in flight)
    asm volatile("s_waitcnt lgkmcnt(0)" ::: "memory");
    __builtin_amdgcn_s_barrier();
    asm volatile("" ::: "memory");
    cur ^= 1;
  }

  // ---- reduction: max over y, sum over x ----
  // acc element (n,i) at lane l: x = w*16 + (l>>4)*4 + i, y = n*16 + (l&15)
  float rm[4];
  #pragma unroll
  for (int i = 0; i < 4; ++i) {
    float v = acc[0][i];
    #pragma unroll
    for (int n = 1; n < 8; ++n) v = fmaxf(v, acc[n][i]);
    rm[i] = v;
  }
  // max across the 16 lanes holding different y for the same x-set
  #pragma unroll
  for (int mask = 1; mask < 16; mask <<= 1)
    #pragma unroll
    for (int i = 0; i < 4; ++i)
      rm[i] = fmaxf(rm[i], __shfl_xor(rm[i], mask, 64));

  // per-lane sum over its 4 distinct x rows, then combine the 4 lane-groups
  float ps = rm[0] + rm[1] + rm[2] + rm[3];
  ps += __shfl_xor(ps, 16, 64);
  ps += __shfl_xor(ps, 32, 64);

  if (lane == 0) wsum[w] = ps;
  __syncthreads();
  if (tid == 0) {
    float s = 0.0f;
    #pragma unroll
    for (int i = 0; i < 8; ++i) s += wsum[i];
    out[bc] = s;
  }
}

extern "C" void kernel_launch(void* const* d_in, const int* in_sizes, int n_in,
                              void* d_out, int out_size, void* d_ws, size_t ws_size,
                              hipStream_t stream) {
  const float* xs = (const float*)d_in[0];
  const float* ys = (const float*)d_in[1];
  float* out = (float*)d_out;
  ur_score_kernel<<<dim3(NB * NC), dim3(512), 0, stream>>>(xs, ys, out);
}